// Round 1
// 313.453 us; speedup vs baseline: 1.0035x; 1.0035x over previous
//
#include <hip/hip_runtime.h>

constexpr int B = 4, L = 1024, H = 768, NH = 12;
constexpr int E = 32, MPE = 4, K = 16, EM = E * MPE;     // EM=128
constexpr int TYPE_DIM = 20;
constexpr int NNODE = E + EM + K;                         // 176
constexpr int NROWS = NNODE + E + EM;                     // 336
constexpr int F = H + TYPE_DIM;                           // 788
constexpr int NCTX = E + EM;                              // 160 context rows

// k_ctx tiling
constexpr int KS = 8;            // l-chunks (partials)
constexpr int KC = L / KS;       // 128 l-steps per chunk
constexpr int RG = 16;           // rows per block (halves seq re-read vs RG=8)
constexpr int CT = 128;          // cols per block (64 threads x float2)
constexpr int NG = NCTX / RG;    // 10 row groups
constexpr int NT = H / CT;       // 6 col tiles

// ---------------------------------------------------------------------------
// Kernel 1: per (b, entity, column-half): head-mean attention rows for the 4
// member mentions + entity row, UNNORMALIZED; per-half row sums written to
// msum/esum (normalization folded into k_ctx staging). grid = B*E*2 = 256
// blocks (all CUs busy), block = 256 (4 waves).
// ---------------------------------------------------------------------------
__global__ __launch_bounds__(256) void k_rows(
        const float* __restrict__ att, const int* __restrict__ mpos,
        float* __restrict__ m_row, float* __restrict__ e_row,
        float* __restrict__ msum, float* __restrict__ esum) {
    int blk = blockIdx.x;
    int be = blk >> 1, half = blk & 1;      // be = b*E + e
    int b = be >> 5;
    int tid = threadIdx.x;
    int c0 = half * 512 + tid * 2;

    int pos[MPE];
    float acc[MPE][2];
#pragma unroll
    for (int mp = 0; mp < MPE; ++mp) {
        pos[mp] = mpos[be * MPE + mp] + 1;
        acc[mp][0] = 0.f; acc[mp][1] = 0.f;
    }
    for (int nh = 0; nh < NH; ++nh) {
#pragma unroll
        for (int mp = 0; mp < MPE; ++mp) {
            const float* row =
                att + (((size_t)(b * NH + nh)) * L + pos[mp]) * L + c0;
            float2 v = *(const float2*)row;
            acc[mp][0] += v.x; acc[mp][1] += v.y;
        }
    }
    // head-mean + per-mention partial (half-row) sums
    float part[MPE];
    float er[2] = {0.f, 0.f};
#pragma unroll
    for (int mp = 0; mp < MPE; ++mp) {
        float s = 0.f;
#pragma unroll
        for (int j = 0; j < 2; ++j) {
            float val = acc[mp][j] * (1.f / NH);
            acc[mp][j] = val; s += val; er[j] += val;
        }
        part[mp] = s;
    }
    // block-reduce the 4 per-mention half-sums
    __shared__ float red[4][MPE];   // [wave][mp]
    int lane = tid & 63, wid = tid >> 6;
#pragma unroll
    for (int mp = 0; mp < MPE; ++mp) {
        float v = part[mp];
#pragma unroll
        for (int o = 32; o; o >>= 1) v += __shfl_down(v, o, 64);
        if (lane == 0) red[wid][mp] = v;
    }
    __syncthreads();
    if (tid < MPE) {
        float s = red[0][tid] + red[1][tid] + red[2][tid] + red[3][tid];
        msum[half * (B * EM) + be * MPE + tid] = s;
    }
    if (tid == 0) {
        float es = 0.f;
#pragma unroll
        for (int mp = 0; mp < MPE; ++mp)
            es += red[0][mp] + red[1][mp] + red[2][mp] + red[3][mp];
        esum[half * (B * E) + be] = 0.25f * es;
    }
    // unnormalized head-mean rows (k_ctx applies the 1/(sum+eps) scale)
#pragma unroll
    for (int mp = 0; mp < MPE; ++mp) {
        float2 w; w.x = acc[mp][0]; w.y = acc[mp][1];
        *(float2*)(m_row + ((size_t)(be * MPE + mp)) * L + c0) = w;
    }
    {
        float2 w; w.x = 0.25f * er[0]; w.y = 0.25f * er[1];
        *(float2*)(e_row + (size_t)be * L + c0) = w;
    }
}

// ---------------------------------------------------------------------------
// Kernel 2: context matmul partials. part[kc][b][r][c] = sum over l-chunk of
// w[r][l]*seq[l][c]. Weights (16 rows x 128 l) are staged NORMALIZED in LDS
// (8 KB) and read as float4 broadcasts (same-address => conflict-free) —
// replaces 64 same-address VMEM loads per 8-l iter with 32 ds_read_b128.
// grid = B*NG*NT*KS = 1920 single-wave blocks (7.5 waves/CU); thread owns
// 2 cols x 16 rows = 32 accs. blockIdx&7 -> XCD; batch b pinned to XCD pair
// {2b,2b+1} for seq L2 locality.
// ---------------------------------------------------------------------------
__global__ __launch_bounds__(64) void k_ctx(
        const float* __restrict__ seq,
        const float* __restrict__ m_row, const float* __restrict__ e_row,
        const float* __restrict__ msum, const float* __restrict__ esum,
        float* __restrict__ part) {
    int blk = blockIdx.x;
    int xcd = blk & 7;
    int b = xcd >> 1;
    int idx = ((blk >> 3) << 1) | (xcd & 1);   // [0, 480) per batch
    int kc = idx & 7;
    int t  = (idx >> 3) % NT;
    int g  = idx / (8 * NT);
    int tid = threadIdx.x;
    int r0 = g * RG;

    __shared__ float w_lds[RG][KC];            // 8 KB
    // stage 16 weight rows, scaled by 1/(rowsum+1e-5). RG=16 => a group is
    // purely entity rows (g<2) or purely mention rows.
#pragma unroll
    for (int it = 0; it < RG; ++it) {
        int r = r0 + it;
        const float* rp; float s;
        if (r < E) {
            rp = e_row + ((size_t)(b * E + r)) * L;
            s = esum[b * E + r] + esum[B * E + b * E + r];
        } else {
            int m = r - E;
            rp = m_row + ((size_t)(b * EM + m)) * L;
            s = msum[b * EM + m] + msum[B * EM + b * EM + m];
        }
        float inv = 1.f / (s + 1e-5f);
        float2 v = *(const float2*)(rp + kc * KC + tid * 2);
        w_lds[it][tid * 2]     = v.x * inv;
        w_lds[it][tid * 2 + 1] = v.y * inv;
    }
    __syncthreads();

    int c = t * CT + tid * 2;
    const float* sp = seq + ((size_t)(b * L + kc * KC)) * H + c;

    float acc[RG][2] = {};
    for (int l0 = 0; l0 < KC; l0 += 8) {
        float2 sv[8];
#pragma unroll
        for (int i = 0; i < 8; ++i)
            sv[i] = *(const float2*)(sp + (size_t)(l0 + i) * H);
#pragma unroll
        for (int ri = 0; ri < RG; ++ri) {
            float4 w0 = *(const float4*)&w_lds[ri][l0];
            float4 w1 = *(const float4*)&w_lds[ri][l0 + 4];
            acc[ri][0] += w0.x * sv[0].x; acc[ri][1] += w0.x * sv[0].y;
            acc[ri][0] += w0.y * sv[1].x; acc[ri][1] += w0.y * sv[1].y;
            acc[ri][0] += w0.z * sv[2].x; acc[ri][1] += w0.z * sv[2].y;
            acc[ri][0] += w0.w * sv[3].x; acc[ri][1] += w0.w * sv[3].y;
            acc[ri][0] += w1.x * sv[4].x; acc[ri][1] += w1.x * sv[4].y;
            acc[ri][0] += w1.y * sv[5].x; acc[ri][1] += w1.y * sv[5].y;
            acc[ri][0] += w1.z * sv[6].x; acc[ri][1] += w1.z * sv[6].y;
            acc[ri][0] += w1.w * sv[7].x; acc[ri][1] += w1.w * sv[7].y;
        }
    }
    float* pp = part + (((size_t)kc * B + b) * NCTX + r0) * H + c;
#pragma unroll
    for (int ri = 0; ri < RG; ++ri) {
        float2 w; w.x = acc[ri][0]; w.y = acc[ri][1];
        *(float2*)(pp + (size_t)ri * H) = w;
    }
}

// ---------------------------------------------------------------------------
// Kernel 3: assembly — entity logsumexp, mention gather, link-span pooling,
// type columns, ctx-partial reduce (now KS=8). grid = B*NROWS, block = 256.
// ---------------------------------------------------------------------------
__global__ __launch_bounds__(256) void k_assemble(
        const float* __restrict__ seq,
        const float* __restrict__ att,
        const float* __restrict__ ttab,
        const int* __restrict__ mpos,
        const int* __restrict__ lstart, const int* __restrict__ llen,
        const float* __restrict__ part,
        float* __restrict__ out) {
    int blk = blockIdx.x;
    int b = blk / NROWS, r = blk % NROWS;
    int tid = threadIdx.x;
    float* orow = out + ((size_t)b * NROWS + r) * F;

    if (r < E) {
        // entity row: logsumexp over the 4 member mention embeddings
        const int* pp = mpos + (b * E + r) * MPE;
        int p0 = pp[0] + 1, p1 = pp[1] + 1, p2 = pp[2] + 1, p3 = pp[3] + 1;
        const float* sb = seq + (size_t)b * L * H;
#pragma unroll
        for (int j = 0; j < 3; ++j) {
            int h = tid + j * 256;
            float x0 = sb[(size_t)p0 * H + h];
            float x1 = sb[(size_t)p1 * H + h];
            float x2 = sb[(size_t)p2 * H + h];
            float x3 = sb[(size_t)p3 * H + h];
            float mx = fmaxf(fmaxf(x0, x1), fmaxf(x2, x3));
            float sm = expf(x0 - mx) + expf(x1 - mx) + expf(x2 - mx) + expf(x3 - mx);
            orow[h] = mx + logf(sm);
        }
        if (tid < TYPE_DIM) orow[H + tid] = ttab[0 * TYPE_DIM + tid];
    } else if (r < E + EM) {
        // mention row: token-embedding gather
        int m = r - E;
        int p = mpos[b * EM + m] + 1;
        const float* srow = seq + ((size_t)b * L + p) * H;
#pragma unroll
        for (int j = 0; j < 3; ++j) orow[tid + j * 256] = srow[tid + j * 256];
        if (tid < TYPE_DIM) orow[H + tid] = ttab[1 * TYPE_DIM + tid];
    } else if (r < NNODE) {
        // link row: span x span head-mean att pooling
        int k = r - (E + EM);
        int s = lstart[b * K + k] + 1;
        int len = llen[b * K + k] + 1;        // span length in [1,32]
        int c = tid & 31, sub = tid >> 5;

        __shared__ float partial[8][32];
        __shared__ float wbuf[32];

        float v = 0.f;
        int pairs = len * NH;
        for (int p = sub; p < pairs; p += 8) {
            int rr = s + p / NH;
            int nh = p % NH;
            v += att[(((size_t)(b * NH + nh)) * L + rr) * L + (s + c)];
        }
        partial[sub][c] = v;
        __syncthreads();
        if (tid < 32) {
            float t = 0.f;
#pragma unroll
            for (int q = 0; q < 8; ++q) t += partial[q][tid];
            wbuf[tid] = t * (1.f / NH);
        }
        __syncthreads();

        const float* sb = seq + (size_t)b * L * H;
        float invlen = 1.f / (float)len;
#pragma unroll
        for (int j = 0; j < 3; ++j) {
            int h = tid + j * 256;
            float acc = 0.f;
            for (int cc = 0; cc < len; ++cc)
                acc += wbuf[cc] * sb[(size_t)(s + cc) * H + h];
            orow[h] = acc * invlen;
        }
        if (tid < TYPE_DIM) orow[H + tid] = ttab[2 * TYPE_DIM + tid];
    } else {
        // ctx row: reduce the KS partials
        int rr = r - NNODE;
        const float* pp = part + ((size_t)b * NCTX + rr) * H;
#pragma unroll
        for (int j = 0; j < 3; ++j) {
            int h = tid + j * 256;
            float s = 0.f;
#pragma unroll
            for (int kc = 0; kc < KS; ++kc)
                s += pp[(size_t)kc * B * NCTX * H + h];
            orow[h] = s;
        }
        if (tid < TYPE_DIM) orow[H + tid] = 0.f;
    }
}

extern "C" void kernel_launch(void* const* d_in, const int* in_sizes, int n_in,
                              void* d_out, int out_size, void* d_ws, size_t ws_size,
                              hipStream_t stream) {
    const float* seq  = (const float*)d_in[0];   // [B,L,H] f32
    const float* att  = (const float*)d_in[1];   // [B,NH,L,L] f32
    const float* ttab = (const float*)d_in[2];   // [3,20] f32
    const int* mpos   = (const int*)d_in[3];     // [B,E,MPE]
    const int* lstart = (const int*)d_in[4];     // [B,K]
    const int* llen   = (const int*)d_in[5];     // [B,K]
    float* out = (float*)d_out;                  // [B,336,788] f32

    float* m_row = (float*)d_ws;                                 // B*EM*L (raw head-mean)
    float* e_row = m_row + (size_t)B * EM * L;                   // B*E*L (raw)
    float* part  = e_row + (size_t)B * E * L;                    // KS*B*160*H
    float* msum  = part + (size_t)KS * B * NCTX * H;             // 2*B*EM half-row sums
    float* esum  = msum + (size_t)2 * B * EM;                    // 2*B*E half-row sums

    k_rows<<<B * E * 2, 256, 0, stream>>>(att, mpos, m_row, e_row, msum, esum);
    k_ctx<<<B * NG * NT * KS, 64, 0, stream>>>(seq, m_row, e_row, msum, esum, part);
    k_assemble<<<B * NROWS, 256, 0, stream>>>(seq, att, ttab, mpos,
                                              lstart, llen, part, out);
}